// Round 5
// baseline (187.597 us; speedup 1.0000x reference)
//
#include <hip/hip_runtime.h>
#include <hip/hip_bf16.h>
#include <stdint.h>

#define VOXEL_SIZE_F 0.4f
#define GAMMA_F 1.1f
#define SLACK_F 0.0625f   // covers all f32 rounding in the triangle-inequality filter

// dx*dx + dy*dy with contraction blocked (bit-exact vs numpy: mul,add both RN)
__device__ __forceinline__ float sq2_rn(float dx, float dy) {
    return __fadd_rn(__fmul_rn(dx, dx), __fmul_rn(dy, dy));
}

// One kernel, one software grid barrier.
// Phase 1: blocks covering V compute voxel mask + per-voxel maxoff record.
// Barrier: device-scope arrival counter (bar zeroed by a memset node).
// Phase 2: block b == ROI b streams the dense record array, candidate-filters
// (triangle inequality: superset of the exact point test), ordered-compacts
// survivors to LDS, exact-tests 16 voxels x 16 pts per round with block-wide
// ordered ballot rank (== stable top_k of a 0/1 mask), early-exits at S.
__global__ __launch_bounds__(256) void k_fused(
    const float* __restrict__ voxels,
    const float* __restrict__ boxes,
    const float* __restrict__ pc_start,
    const int* __restrict__ coords,
    const int* __restrict__ num_points,
    int V, int R, int K, int F, int S,
    float4* __restrict__ recq,
    int* __restrict__ bar,
    float* __restrict__ out_kp,
    float* __restrict__ out_mask,
    float* __restrict__ out_vox)
{
    __shared__ float qx[256], qy[256], rv[256];
    __shared__ float4 cq[256];
    __shared__ int wsum[4];
    int tid = threadIdx.x, lane = tid & 63, wid = tid >> 6;
    int b = blockIdx.x;
    unsigned long long ltmask = (1ull << lane) - 1ull;
    float psx = pc_start[0], psy = pc_start[1];

    // ---------------- Phase 1: voxel mask + maxoff record -------------------
    int v = b * 256 + tid;
    if (b * 256 < V) {
        for (int j = tid; j < R; j += 256) {        // stage boxes (R<=256)
            const float* bp = boxes + (size_t)j * 7;
            float hx = bp[3] * 0.5f, hy = bp[4] * 0.5f;
            qx[j] = (bp[0] - psx) / VOXEL_SIZE_F;
            qy[j] = (bp[1] - psy) / VOXEL_SIZE_F;
            rv[j] = (sqrtf(sq2_rn(hx, hy)) * GAMMA_F) / VOXEL_SIZE_F;
        }
        __syncthreads();
        if (v < V) {
            float cxf = (float)coords[2 * v], cyf = (float)coords[2 * v + 1];
            int np = num_points[v];
            np = np < 0 ? 0 : (np > K ? K : np);
            int m = 0;
            #pragma unroll 4
            for (int j = 0; j < R; j++) {
                float dx = qx[j] - cxf, dy = qy[j] - cyf;
                m |= (sqrtf(sq2_rn(dx, dy)) < rv[j]) ? 1 : 0;   // strict <
            }
            float cxm = cxf * VOXEL_SIZE_F + psx;
            float cym = cyf * VOXEL_SIZE_F + psy;
            float mo = -1e30f;      // inactive / empty -> candidate test false
            if (m && np > 0) {
                const float* pv = voxels + (size_t)v * K * F;
                #pragma unroll 4
                for (int k = 0; k < K; k++) {   // reading k>=np is safe (K slots)
                    float px = pv[k * F + 0], py = pv[k * F + 1];
                    float d = sqrtf(sq2_rn(px - cxm, py - cym));
                    if (k < np) mo = fmaxf(mo, d);
                }
            }
            float4 q;
            q.x = cxm; q.y = cym; q.z = mo;
            q.w = __int_as_float(v | (np << 16));
            recq[v] = q;
            out_vox[v] = m ? 1.0f : 0.0f;
        }
    }

    // ---------------- grid barrier (all blocks co-resident) -----------------
    __syncthreads();
    __threadfence();                              // release phase-1 stores
    if (tid == 0) {
        __hip_atomic_fetch_add(bar, 1, __ATOMIC_ACQ_REL, __HIP_MEMORY_SCOPE_AGENT);
        while (__hip_atomic_load(bar, __ATOMIC_ACQUIRE, __HIP_MEMORY_SCOPE_AGENT)
               < (int)gridDim.x)
            __builtin_amdgcn_s_sleep(8);
    }
    __syncthreads();
    __threadfence();                              // acquire for whole block

    // ---------------- Phase 2: one ROI per block ----------------------------
    int r = b;
    if (r < R) {
        const float* bp = boxes + (size_t)r * 7;
        float bx = bp[0], by = bp[1];
        float rad = sqrtf(sq2_rn(bp[3] * 0.5f, bp[4] * 0.5f)) * GAMMA_F;
        int count = 0;

        for (int c0 = 0; c0 < V && count < S; c0 += 256) {
            int i = c0 + tid;
            int pred = 0;
            float4 q = make_float4(0.f, 0.f, 0.f, 0.f);
            if (i < V) {
                q = recq[i];
                float d = sqrtf(sq2_rn(q.x - bx, q.y - by));
                pred = (d <= rad + q.z + SLACK_F) ? 1 : 0;   // mo=-1e30 => false
            }
            int tot = __syncthreads_count(pred);
            if (tot == 0) continue;                // fast path: 1 sync, no LDS

            unsigned long long bal = __ballot(pred != 0);
            if (lane == 0) wsum[wid] = __popcll(bal);
            __syncthreads();
            int cb = 0;
            for (int w2 = 0; w2 < wid; w2++) cb += wsum[w2];
            if (pred) cq[cb + __popcll(bal & ltmask)] = q;
            __syncthreads();

            for (int g0 = 0; g0 < tot && count < S; g0 += 16) {
                int ci = g0 + (tid >> 4), k = tid & 15;
                int pred2 = 0;
                size_t n = 0;
                if (ci < tot) {
                    float4 qq = cq[ci];
                    int vn = __float_as_int(qq.w);
                    int npv = vn >> 16, vid = vn & 0xFFFF;
                    if (k < npv) {
                        n = (size_t)vid * K + k;
                        float px = voxels[n * F + 0], py = voxels[n * F + 1];
                        pred2 = (sqrtf(sq2_rn(px - bx, py - by)) <= rad) ? 1 : 0;
                    }
                }
                unsigned long long bal2 = __ballot(pred2 != 0);
                if (lane == 0) wsum[wid] = __popcll(bal2);
                __syncthreads();
                int wb = count;
                for (int w2 = 0; w2 < wid; w2++) wb += wsum[w2];
                int tot2 = wsum[0] + wsum[1] + wsum[2] + wsum[3];
                int pos = wb + __popcll(bal2 & ltmask);
                if (pred2 && pos < S) {
                    const float* src = voxels + n * F;
                    float* dst = out_kp + ((size_t)r * S + pos) * F;
                    #pragma unroll
                    for (int j = 0; j < 5; j++) dst[j] = src[j];
                }
                count += tot2;
                __syncthreads();
            }
        }

        int sc = count < S ? count : S;
        for (int s = tid; s < S; s += 256)
            out_mask[(size_t)r * S + s] = (s < sc) ? 1.0f : 0.0f;
        for (int j = tid; j < S * F; j += 256) {
            int s = j / F;
            if (s >= sc) out_kp[(size_t)r * S * F + j] = 0.0f;
        }
    }
}

extern "C" void kernel_launch(void* const* d_in, const int* in_sizes, int n_in,
                              void* d_out, int out_size, void* d_ws, size_t ws_size,
                              hipStream_t stream) {
    const float* voxels   = (const float*)d_in[0];
    const float* boxes    = (const float*)d_in[1];
    const float* pc_start = (const float*)d_in[2];
    const int*   coords   = (const int*)d_in[3];
    const int*   num_pts  = (const int*)d_in[4];

    int V = in_sizes[4];                     // 20000
    int R = in_sizes[1] / 7;                 // 256
    int K = 16;
    int F = (in_sizes[0] / V) / K;           // 5
    int S = (out_size - V) / (R * (F + 1));  // 128

    float* out_kp  = (float*)d_out;                 // [R,S,F]
    float* out_msk = out_kp + (size_t)R * S * F;    // [R,S]
    float* out_vox = out_msk + (size_t)R * S;       // [V]

    char* w = (char*)d_ws;
    auto carve = [&](size_t bytes) {
        void* p = (void*)w;
        w += (bytes + 255) & ~(size_t)255;
        return p;
    };
    int*    bar  = (int*)carve(4);
    float4* recq = (float4*)carve((size_t)V * 16);

    int NB = (V + 255) / 256;
    if (NB < R) NB = R;                      // 256 blocks; all co-resident

    hipMemsetAsync(bar, 0, sizeof(int), stream);   // graph-capturable node
    k_fused<<<NB, 256, 0, stream>>>(voxels, boxes, pc_start, coords, num_pts,
                                    V, R, K, F, S, recq, bar,
                                    out_kp, out_msk, out_vox);
}

// Round 7
// 127.270 us; speedup vs baseline: 1.4740x; 1.4740x over previous
//
#include <hip/hip_runtime.h>
#include <hip/hip_bf16.h>
#include <stdint.h>

#define VOXEL_SIZE_F 0.4f
#define GAMMA_F 1.1f
#define SLACK_F 0.0625f   // covers all f32 rounding in the triangle-inequality filter
#define NCH_MAX 128       // supports V <= 32768 (V = 20000 here)
#define CAP 2048          // candidate batch capacity

// dx*dx + dy*dy with contraction blocked (bit-exact vs numpy: mul,add both RN)
__device__ __forceinline__ float sq2_rn(float dx, float dy) {
    return __fadd_rn(__fmul_rn(dx, dx), __fmul_rn(dy, dy));
}

__device__ __forceinline__ int wave_incl_scan(int v, int lane) {
    #pragma unroll
    for (int d = 1; d < 64; d <<= 1) {
        int t = __shfl_up(v, d, 64);
        if (lane >= d) v += t;
    }
    return v;
}

// ---- K1: voxel mask + per-voxel maxoff, dense float4 record ----------------
// record[v] = {center_x_m, center_y_m, maxoff (or -1e30), bits(vid | np<<16)}
__global__ __launch_bounds__(256) void k1_mask(
    const float* __restrict__ boxes,
    const float* __restrict__ pc_start,
    const int* __restrict__ coords,
    const int* __restrict__ num_points,
    const float* __restrict__ voxels,
    int V, int R, int K, int F,
    float4* __restrict__ recq,
    float* __restrict__ out_vox)
{
    __shared__ float qx[256], qy[256], rv[256];
    int tid = threadIdx.x;
    int v = blockIdx.x * 256 + tid;
    float psx = pc_start[0], psy = pc_start[1];
    float cxf = 0.f, cyf = 0.f;
    int np = 0;
    if (v < V) {
        cxf = (float)coords[2 * v];
        cyf = (float)coords[2 * v + 1];
        np = num_points[v];
        np = np < 0 ? 0 : (np > K ? K : np);
    }
    int m = 0;
    for (int rb = 0; rb < R; rb += 256) {
        int tile = (R - rb) < 256 ? (R - rb) : 256;
        for (int j = tid; j < tile; j += 256) {
            const float* bp = boxes + (size_t)(rb + j) * 7;
            float hx = bp[3] * 0.5f, hy = bp[4] * 0.5f;
            qx[j] = (bp[0] - psx) / VOXEL_SIZE_F;
            qy[j] = (bp[1] - psy) / VOXEL_SIZE_F;
            rv[j] = (sqrtf(sq2_rn(hx, hy)) * GAMMA_F) / VOXEL_SIZE_F;
        }
        __syncthreads();
        #pragma unroll 4
        for (int j = 0; j < tile; j++) {
            float dx = qx[j] - cxf, dy = qy[j] - cyf;
            m |= (sqrtf(sq2_rn(dx, dy)) < rv[j]) ? 1 : 0;   // strict < (reference)
        }
        __syncthreads();
    }
    if (v < V) {
        float cxm = cxf * VOXEL_SIZE_F + psx;
        float cym = cyf * VOXEL_SIZE_F + psy;
        float mo = -1e30f;       // inactive or empty -> prefilter always false
        if (m && np > 0) {
            const float* pv = voxels + (size_t)v * K * F;
            for (int k = 0; k < np; k++) {
                float px = pv[k * F + 0], py = pv[k * F + 1];
                mo = fmaxf(mo, sqrtf(sq2_rn(px - cxm, py - cym)));
            }
        }
        float4 q;
        q.x = cxm; q.y = cym; q.z = mo;
        q.w = __int_as_float(v | (np << 16));
        recq[v] = q;
        out_vox[v] = m ? 1.0f : 0.0f;
    }
}

// ---- K2: one block per ROI — sync-free prefilter + ordered exact select ----
__global__ __launch_bounds__(256) void k2_roi(
    const float* __restrict__ voxels,
    const float* __restrict__ boxes,
    const float4* __restrict__ recq,
    int V, int K, int F, int S,
    float* __restrict__ out_kp,
    float* __restrict__ out_mask)
{
    __shared__ unsigned long long bm[NCH_MAX * 4];   // per-(chunk,wave) ballots
    __shared__ int pfx[NCH_MAX * 4];                 // exclusive prefix per word
    __shared__ int clist[CAP];                       // ordered candidates (vid|np<<16)
    __shared__ int wsum[4];
    __shared__ int s_total;

    int r = blockIdx.x;
    int tid = threadIdx.x, lane = tid & 63, wid = tid >> 6;
    unsigned long long ltmask = (1ull << lane) - 1ull;

    const float* bp = boxes + (size_t)r * 7;
    float bx = bp[0], by = bp[1];
    float rad = sqrtf(sq2_rn(bp[3] * 0.5f, bp[4] * 0.5f)) * GAMMA_F;

    int nch = (V + 255) >> 8;
    int NW = nch << 2;

    // 1) prefilter: NO block syncs in the loop -> loads pipeline freely
    for (int c = 0; c < nch; c++) {
        int i = (c << 8) + tid;
        int pred = 0;
        if (i < V) {
            float4 q = recq[i];
            float d = sqrtf(sq2_rn(q.x - bx, q.y - by));
            pred = (d <= rad + q.z + SLACK_F) ? 1 : 0;   // superset of point test
        }
        unsigned long long bal = __ballot(pred != 0);
        if (lane == 0) bm[(c << 2) + wid] = bal;
    }
    __syncthreads();

    // 2) exclusive prefix over ballot words (word order == point-index order)
    if (wid == 0) {
        int run = 0;
        for (int w0 = 0; w0 < NW; w0 += 64) {
            int w = w0 + lane;
            int val = (w < NW) ? __popcll(bm[w]) : 0;
            int incl = wave_incl_scan(val, lane);
            if (w < NW) pfx[w] = run + incl - val;
            run += __shfl(incl, 63, 64);
        }
        if (lane == 0) s_total = run;
    }
    __syncthreads();
    int T = s_total;
    int count = 0;

    // 3) batches of candidates: ordered rank-scatter, then exact-test rounds
    for (int b0 = 0; b0 < T && count < S; b0 += CAP) {
        for (int c = 0; c < nch; c++) {
            int w = (c << 2) + wid;
            unsigned long long bal = bm[w];
            if ((bal >> lane) & 1ull) {
                int rank = pfx[w] + __popcll(bal & ltmask);
                int rr = rank - b0;
                if (rr >= 0 && rr < CAP) {
                    int i = (c << 8) + tid;
                    clist[rr] = __float_as_int(recq[i].w);   // vid | np<<16
                }
            }
        }
        __syncthreads();
        int bt = T - b0; if (bt > CAP) bt = CAP;

        for (int g0 = 0; g0 < bt && count < S; g0 += 16) {
            int ci = g0 + (tid >> 4), k = tid & 15;
            int pred2 = 0;
            size_t n = 0;
            if (ci < bt) {
                int vn = clist[ci];
                int npv = vn >> 16, vid = vn & 0xFFFF;
                if (k < npv) {
                    n = (size_t)vid * K + k;
                    float px = voxels[n * F + 0], py = voxels[n * F + 1];
                    pred2 = (sqrtf(sq2_rn(px - bx, py - by)) <= rad) ? 1 : 0;
                }
            }
            unsigned long long bal2 = __ballot(pred2 != 0);
            if (lane == 0) wsum[wid] = __popcll(bal2);
            __syncthreads();
            int wb = count;
            for (int w2 = 0; w2 < wid; w2++) wb += wsum[w2];
            int tot2 = wsum[0] + wsum[1] + wsum[2] + wsum[3];
            int pos = wb + __popcll(bal2 & ltmask);
            if (pred2 && pos < S) {
                const float* src = voxels + n * F;
                float* dst = out_kp + ((size_t)r * S + pos) * F;
                #pragma unroll
                for (int j = 0; j < 5; j++) dst[j] = src[j];
            }
            count += tot2;
            __syncthreads();
        }
        __syncthreads();   // clist safe to reuse next batch
    }

    // 4) mask + zero tail
    int sc = count < S ? count : S;
    for (int s = tid; s < S; s += 256)
        out_mask[(size_t)r * S + s] = (s < sc) ? 1.0f : 0.0f;
    for (int j = tid; j < S * F; j += 256) {
        int s = j / F;
        if (s >= sc) out_kp[(size_t)r * S * F + j] = 0.0f;
    }
}

extern "C" void kernel_launch(void* const* d_in, const int* in_sizes, int n_in,
                              void* d_out, int out_size, void* d_ws, size_t ws_size,
                              hipStream_t stream) {
    const float* voxels   = (const float*)d_in[0];
    const float* boxes    = (const float*)d_in[1];
    const float* pc_start = (const float*)d_in[2];
    const int*   coords   = (const int*)d_in[3];
    const int*   num_pts  = (const int*)d_in[4];

    int V = in_sizes[4];                     // 20000
    int R = in_sizes[1] / 7;                 // 256
    int K = 16;
    int F = (in_sizes[0] / V) / K;           // 5
    int S = (out_size - V) / (R * (F + 1));  // 128

    float* out_kp  = (float*)d_out;                 // [R,S,F]
    float* out_msk = out_kp + (size_t)R * S * F;    // [R,S]
    float* out_vox = out_msk + (size_t)R * S;       // [V]

    float4* recq = (float4*)d_ws;                   // V * 16 B

    int nb1 = (V + 255) / 256;                      // 79
    k1_mask<<<nb1, 256, 0, stream>>>(boxes, pc_start, coords, num_pts, voxels,
                                     V, R, K, F, recq, out_vox);
    k2_roi<<<R, 256, 0, stream>>>(voxels, boxes, recq, V, K, F, S,
                                  out_kp, out_msk);
}

// Round 9
// 114.444 us; speedup vs baseline: 1.6392x; 1.1121x over previous
//
#include <hip/hip_runtime.h>
#include <hip/hip_bf16.h>
#include <stdint.h>

#define VOXEL_SIZE_F 0.4f
#define GAMMA_F 1.1f
#define SLACK_F 0.0625f   // covers all f32 rounding in the triangle-inequality filter
#define NCH_MAX 128       // supports V <= 32768 (V = 20000 here)
#define CAP 2048          // candidate batch capacity

// dx*dx + dy*dy with contraction blocked (bit-exact vs numpy: mul,add both RN)
__device__ __forceinline__ float sq2_rn(float dx, float dy) {
    return __fadd_rn(__fmul_rn(dx, dx), __fmul_rn(dy, dy));
}

__device__ __forceinline__ int wave_incl_scan(int v, int lane) {
    #pragma unroll
    for (int d = 1; d < 64; d <<= 1) {
        int t = __shfl_up(v, d, 64);
        if (lane >= d) v += t;
    }
    return v;
}

// ---- K1: voxel mask + per-voxel maxoff, dense float4 record ----------------
// record[v] = {center_x_m, center_y_m, maxoff (or -1e30), bits(vid | np<<16)}
__global__ __launch_bounds__(256) void k1_mask(
    const float* __restrict__ boxes,
    const float* __restrict__ pc_start,
    const int* __restrict__ coords,
    const int* __restrict__ num_points,
    const float* __restrict__ voxels,
    int V, int R, int K, int F,
    float4* __restrict__ recq,
    float* __restrict__ out_vox)
{
    __shared__ float qx[256], qy[256], rv[256];
    int tid = threadIdx.x;
    int v = blockIdx.x * 256 + tid;
    float psx = pc_start[0], psy = pc_start[1];
    float cxf = 0.f, cyf = 0.f;
    int np = 0;
    if (v < V) {
        cxf = (float)coords[2 * v];
        cyf = (float)coords[2 * v + 1];
        np = num_points[v];
        np = np < 0 ? 0 : (np > K ? K : np);
    }
    int m = 0;
    for (int rb = 0; rb < R; rb += 256) {
        int tile = (R - rb) < 256 ? (R - rb) : 256;
        for (int j = tid; j < tile; j += 256) {
            const float* bp = boxes + (size_t)(rb + j) * 7;
            float hx = bp[3] * 0.5f, hy = bp[4] * 0.5f;
            qx[j] = (bp[0] - psx) / VOXEL_SIZE_F;
            qy[j] = (bp[1] - psy) / VOXEL_SIZE_F;
            rv[j] = (sqrtf(sq2_rn(hx, hy)) * GAMMA_F) / VOXEL_SIZE_F;
        }
        __syncthreads();
        #pragma unroll 4
        for (int j = 0; j < tile; j++) {
            float dx = qx[j] - cxf, dy = qy[j] - cyf;
            m |= (sqrtf(sq2_rn(dx, dy)) < rv[j]) ? 1 : 0;   // strict < (reference)
        }
        __syncthreads();
    }
    if (v < V) {
        float cxm = cxf * VOXEL_SIZE_F + psx;
        float cym = cyf * VOXEL_SIZE_F + psy;
        float mo = -1e30f;       // inactive or empty -> prefilter always false
        if (m && np > 0) {
            const float* pv = voxels + (size_t)v * K * F;
            for (int k = 0; k < np; k++) {
                float px = pv[k * F + 0], py = pv[k * F + 1];
                mo = fmaxf(mo, sqrtf(sq2_rn(px - cxm, py - cym)));
            }
        }
        float4 q;
        q.x = cxm; q.y = cym; q.z = mo;
        q.w = __int_as_float(v | (np << 16));
        recq[v] = q;
        out_vox[v] = m ? 1.0f : 0.0f;
    }
}

// ---- K2: one block per ROI — MLP-unrolled prefilter + ordered exact select -
__global__ __launch_bounds__(256) void k2_roi(
    const float* __restrict__ voxels,
    const float* __restrict__ boxes,
    const float4* __restrict__ recq,
    int V, int K, int F, int S,
    float* __restrict__ out_kp,
    float* __restrict__ out_mask)
{
    __shared__ unsigned long long bm[NCH_MAX * 4];   // per-(chunk,wave) ballots
    __shared__ int pfx[NCH_MAX * 4];                 // exclusive prefix per word
    __shared__ int clist[CAP];                       // ordered candidates (vid|np<<16)
    __shared__ int wsum[4];
    __shared__ int s_total;

    int r = blockIdx.x;
    int tid = threadIdx.x, lane = tid & 63, wid = tid >> 6;
    unsigned long long ltmask = (1ull << lane) - 1ull;

    const float* bp = boxes + (size_t)r * 7;
    float bx = bp[0], by = bp[1];
    float rad = sqrtf(sq2_rn(bp[3] * 0.5f, bp[4] * 0.5f)) * GAMMA_F;

    int nch = (V + 255) >> 8;
    int NW = nch << 2;
    int Vc = V - 1;

    // 1) prefilter, unrolled x4: 4 independent loads in flight per batch.
    //    Clamped load index keeps OOB lanes inside recq; pred still needs i<V.
    int nch4 = nch & ~3;
    int c = 0;
    for (; c < nch4; c += 4) {
        int i0 = ((c + 0) << 8) + tid;
        int i1 = ((c + 1) << 8) + tid;
        int i2 = ((c + 2) << 8) + tid;
        int i3 = ((c + 3) << 8) + tid;
        float4 q0 = recq[i0 < Vc ? i0 : Vc];
        float4 q1 = recq[i1 < Vc ? i1 : Vc];
        float4 q2 = recq[i2 < Vc ? i2 : Vc];
        float4 q3 = recq[i3 < Vc ? i3 : Vc];
        int p0 = (i0 < V) && (sqrtf(sq2_rn(q0.x - bx, q0.y - by)) <= rad + q0.z + SLACK_F);
        int p1 = (i1 < V) && (sqrtf(sq2_rn(q1.x - bx, q1.y - by)) <= rad + q1.z + SLACK_F);
        int p2 = (i2 < V) && (sqrtf(sq2_rn(q2.x - bx, q2.y - by)) <= rad + q2.z + SLACK_F);
        int p3 = (i3 < V) && (sqrtf(sq2_rn(q3.x - bx, q3.y - by)) <= rad + q3.z + SLACK_F);
        unsigned long long b0 = __ballot(p0 != 0);
        unsigned long long b1 = __ballot(p1 != 0);
        unsigned long long b2 = __ballot(p2 != 0);
        unsigned long long b3 = __ballot(p3 != 0);
        if (lane == 0) {
            bm[((c + 0) << 2) + wid] = b0;
            bm[((c + 1) << 2) + wid] = b1;
            bm[((c + 2) << 2) + wid] = b2;
            bm[((c + 3) << 2) + wid] = b3;
        }
    }
    for (; c < nch; c++) {
        int i = (c << 8) + tid;
        float4 q = recq[i < Vc ? i : Vc];
        int p = (i < V) && (sqrtf(sq2_rn(q.x - bx, q.y - by)) <= rad + q.z + SLACK_F);
        unsigned long long bal = __ballot(p != 0);
        if (lane == 0) bm[(c << 2) + wid] = bal;
    }
    __syncthreads();

    // 2) exclusive prefix over ballot words (word order == point-index order)
    if (wid == 0) {
        int run = 0;
        for (int w0 = 0; w0 < NW; w0 += 64) {
            int w = w0 + lane;
            int val = (w < NW) ? __popcll(bm[w]) : 0;
            int incl = wave_incl_scan(val, lane);
            if (w < NW) pfx[w] = run + incl - val;
            run += __shfl(incl, 63, 64);
        }
        if (lane == 0) s_total = run;
    }
    __syncthreads();
    int T = s_total;
    int count = 0;

    // 3) batches of candidates: ordered rank-scatter, then exact-test rounds
    for (int b0 = 0; b0 < T && count < S; b0 += CAP) {
        int cc = 0;
        for (; cc + 4 <= nch; cc += 4) {
            unsigned long long a0 = bm[((cc + 0) << 2) + wid];
            unsigned long long a1 = bm[((cc + 1) << 2) + wid];
            unsigned long long a2 = bm[((cc + 2) << 2) + wid];
            unsigned long long a3 = bm[((cc + 3) << 2) + wid];
            #pragma unroll
            for (int u = 0; u < 4; u++) {
                unsigned long long bal = u == 0 ? a0 : (u == 1 ? a1 : (u == 2 ? a2 : a3));
                if ((bal >> lane) & 1ull) {
                    int w = ((cc + u) << 2) + wid;
                    int rank = pfx[w] + __popcll(bal & ltmask);
                    int rr = rank - b0;
                    if (rr >= 0 && rr < CAP) {
                        int i = ((cc + u) << 8) + tid;
                        clist[rr] = __float_as_int(recq[i].w);   // vid | np<<16
                    }
                }
            }
        }
        for (; cc < nch; cc++) {
            unsigned long long bal = bm[(cc << 2) + wid];
            if ((bal >> lane) & 1ull) {
                int w = (cc << 2) + wid;
                int rank = pfx[w] + __popcll(bal & ltmask);
                int rr = rank - b0;
                if (rr >= 0 && rr < CAP) {
                    int i = (cc << 8) + tid;
                    clist[rr] = __float_as_int(recq[i].w);
                }
            }
        }
        __syncthreads();
        int bt = T - b0; if (bt > CAP) bt = CAP;

        for (int g0 = 0; g0 < bt && count < S; g0 += 16) {
            int ci = g0 + (tid >> 4), k = tid & 15;
            int pred2 = 0;
            size_t n = 0;
            if (ci < bt) {
                int vn = clist[ci];
                int npv = vn >> 16, vid = vn & 0xFFFF;
                if (k < npv) {
                    n = (size_t)vid * K + k;
                    float px = voxels[n * F + 0], py = voxels[n * F + 1];
                    pred2 = (sqrtf(sq2_rn(px - bx, py - by)) <= rad) ? 1 : 0;
                }
            }
            unsigned long long bal2 = __ballot(pred2 != 0);
            if (lane == 0) wsum[wid] = __popcll(bal2);
            __syncthreads();
            int wb = count;
            for (int w2 = 0; w2 < wid; w2++) wb += wsum[w2];
            int tot2 = wsum[0] + wsum[1] + wsum[2] + wsum[3];
            int pos = wb + __popcll(bal2 & ltmask);
            if (pred2 && pos < S) {
                const float* src = voxels + n * F;
                float* dst = out_kp + ((size_t)r * S + pos) * F;
                #pragma unroll
                for (int j = 0; j < 5; j++) dst[j] = src[j];
            }
            count += tot2;
            __syncthreads();
        }
        __syncthreads();   // clist safe to reuse next batch
    }

    // 4) mask + zero tail
    int sc = count < S ? count : S;
    for (int s = tid; s < S; s += 256)
        out_mask[(size_t)r * S + s] = (s < sc) ? 1.0f : 0.0f;
    for (int j = tid; j < S * F; j += 256) {
        int s = j / F;
        if (s >= sc) out_kp[(size_t)r * S * F + j] = 0.0f;
    }
}

extern "C" void kernel_launch(void* const* d_in, const int* in_sizes, int n_in,
                              void* d_out, int out_size, void* d_ws, size_t ws_size,
                              hipStream_t stream) {
    const float* voxels   = (const float*)d_in[0];
    const float* boxes    = (const float*)d_in[1];
    const float* pc_start = (const float*)d_in[2];
    const int*   coords   = (const int*)d_in[3];
    const int*   num_pts  = (const int*)d_in[4];

    int V = in_sizes[4];                     // 20000
    int R = in_sizes[1] / 7;                 // 256
    int K = 16;
    int F = (in_sizes[0] / V) / K;           // 5
    int S = (out_size - V) / (R * (F + 1));  // 128

    float* out_kp  = (float*)d_out;                 // [R,S,F]
    float* out_msk = out_kp + (size_t)R * S * F;    // [R,S]
    float* out_vox = out_msk + (size_t)R * S;       // [V]

    float4* recq = (float4*)d_ws;                   // V * 16 B

    int nb1 = (V + 255) / 256;                      // 79
    k1_mask<<<nb1, 256, 0, stream>>>(boxes, pc_start, coords, num_pts, voxels,
                                     V, R, K, F, recq, out_vox);
    k2_roi<<<R, 256, 0, stream>>>(voxels, boxes, recq, V, K, F, S,
                                  out_kp, out_msk);
}

// Round 10
// 100.321 us; speedup vs baseline: 1.8700x; 1.1408x over previous
//
#include <hip/hip_runtime.h>
#include <hip/hip_bf16.h>
#include <stdint.h>

#define VOXEL_SIZE_F 0.4f
#define GAMMA_F 1.1f
#define SLACK_F 0.0625f   // covers all f32 rounding in the triangle-inequality filter
#define NCHM 64           // 512-pt chunks: supports V <= 32768 (V = 20000 here)
#define WAVES 8           // k2 block = 512 threads
#define CAP 2048          // candidate batch capacity

// dx*dx + dy*dy with contraction blocked (bit-exact vs numpy: mul,add both RN)
__device__ __forceinline__ float sq2_rn(float dx, float dy) {
    return __fadd_rn(__fmul_rn(dx, dx), __fmul_rn(dy, dy));
}

__device__ __forceinline__ int wave_incl_scan(int v, int lane) {
    #pragma unroll
    for (int d = 1; d < 64; d <<= 1) {
        int t = __shfl_up(v, d, 64);
        if (lane >= d) v += t;
    }
    return v;
}

// ---- K1: voxel mask + per-voxel maxoff, dense float4 record ----------------
// record[v] = {center_x_m, center_y_m, maxoff (or -1e30), bits(vid | np<<16)}
__global__ __launch_bounds__(256) void k1_mask(
    const float* __restrict__ boxes,
    const float* __restrict__ pc_start,
    const int* __restrict__ coords,
    const int* __restrict__ num_points,
    const float* __restrict__ voxels,
    int V, int R, int K, int F,
    float4* __restrict__ recq,
    float* __restrict__ out_vox)
{
    __shared__ float qx[256], qy[256], rv[256];
    int tid = threadIdx.x;
    int v = blockIdx.x * 256 + tid;
    float psx = pc_start[0], psy = pc_start[1];
    float cxf = 0.f, cyf = 0.f;
    int np = 0;
    if (v < V) {
        cxf = (float)coords[2 * v];
        cyf = (float)coords[2 * v + 1];
        np = num_points[v];
        np = np < 0 ? 0 : (np > K ? K : np);
    }
    int m = 0;
    for (int rb = 0; rb < R; rb += 256) {
        int tile = (R - rb) < 256 ? (R - rb) : 256;
        for (int j = tid; j < tile; j += 256) {
            const float* bp = boxes + (size_t)(rb + j) * 7;
            float hx = bp[3] * 0.5f, hy = bp[4] * 0.5f;
            qx[j] = (bp[0] - psx) / VOXEL_SIZE_F;
            qy[j] = (bp[1] - psy) / VOXEL_SIZE_F;
            rv[j] = (sqrtf(sq2_rn(hx, hy)) * GAMMA_F) / VOXEL_SIZE_F;
        }
        __syncthreads();
        #pragma unroll 4
        for (int j = 0; j < tile; j++) {
            float dx = qx[j] - cxf, dy = qy[j] - cyf;
            m |= (sqrtf(sq2_rn(dx, dy)) < rv[j]) ? 1 : 0;   // strict < (reference)
        }
        __syncthreads();
    }
    if (v < V) {
        float cxm = cxf * VOXEL_SIZE_F + psx;
        float cym = cyf * VOXEL_SIZE_F + psy;
        float mo = -1e30f;       // inactive or empty -> prefilter always false
        if (m && np > 0) {
            const float* pv = voxels + (size_t)v * K * F;
            if (K == 16) {
                // MLP path: 32 independent loads in flight, then reduce.
                float pxv[16], pyv[16];
                #pragma unroll
                for (int k = 0; k < 16; k++) {
                    pxv[k] = pv[k * F + 0];
                    pyv[k] = pv[k * F + 1];
                }
                #pragma unroll
                for (int k = 0; k < 16; k++) {
                    float d = sqrtf(sq2_rn(pxv[k] - cxm, pyv[k] - cym));
                    if (k < np) mo = fmaxf(mo, d);   // identical arithmetic
                }
            } else {
                for (int k = 0; k < np; k++) {
                    float px = pv[k * F + 0], py = pv[k * F + 1];
                    mo = fmaxf(mo, sqrtf(sq2_rn(px - cxm, py - cym)));
                }
            }
        }
        float4 q;
        q.x = cxm; q.y = cym; q.z = mo;
        q.w = __int_as_float(v | (np << 16));
        recq[v] = q;
        out_vox[v] = m ? 1.0f : 0.0f;
    }
}

// ---- K2: one block (8 waves) per ROI — MLP prefilter + ordered select ------
__global__ __launch_bounds__(512) void k2_roi(
    const float* __restrict__ voxels,
    const float* __restrict__ boxes,
    const float4* __restrict__ recq,
    int V, int K, int F, int S,
    float* __restrict__ out_kp,
    float* __restrict__ out_mask)
{
    __shared__ unsigned long long bm[NCHM * WAVES];  // per-(chunk,wave) ballots
    __shared__ int pfx[NCHM * WAVES];                // exclusive prefix per word
    __shared__ int clist[CAP];                       // ordered candidates (vid|np<<16)
    __shared__ int wsum[WAVES];
    __shared__ int s_total;

    int r = blockIdx.x;
    int tid = threadIdx.x, lane = tid & 63, wid = tid >> 6;
    unsigned long long ltmask = (1ull << lane) - 1ull;

    const float* bp = boxes + (size_t)r * 7;
    float bx = bp[0], by = bp[1];
    float rad = sqrtf(sq2_rn(bp[3] * 0.5f, bp[4] * 0.5f)) * GAMMA_F;

    int nch = (V + 511) >> 9;          // 512-point chunks (40 for V=20000)
    int NW = nch << 3;                 // ballot words
    int Vc = V - 1;

    // 1) prefilter, unrolled x4: 4 independent loads in flight per batch.
    //    Clamped load index keeps OOB lanes inside recq; pred still needs i<V.
    int nch4 = nch & ~3;
    int c = 0;
    for (; c < nch4; c += 4) {
        int i0 = ((c + 0) << 9) + tid;
        int i1 = ((c + 1) << 9) + tid;
        int i2 = ((c + 2) << 9) + tid;
        int i3 = ((c + 3) << 9) + tid;
        float4 q0 = recq[i0 < Vc ? i0 : Vc];
        float4 q1 = recq[i1 < Vc ? i1 : Vc];
        float4 q2 = recq[i2 < Vc ? i2 : Vc];
        float4 q3 = recq[i3 < Vc ? i3 : Vc];
        int p0 = (i0 < V) && (sqrtf(sq2_rn(q0.x - bx, q0.y - by)) <= rad + q0.z + SLACK_F);
        int p1 = (i1 < V) && (sqrtf(sq2_rn(q1.x - bx, q1.y - by)) <= rad + q1.z + SLACK_F);
        int p2 = (i2 < V) && (sqrtf(sq2_rn(q2.x - bx, q2.y - by)) <= rad + q2.z + SLACK_F);
        int p3 = (i3 < V) && (sqrtf(sq2_rn(q3.x - bx, q3.y - by)) <= rad + q3.z + SLACK_F);
        unsigned long long b0 = __ballot(p0 != 0);
        unsigned long long b1 = __ballot(p1 != 0);
        unsigned long long b2 = __ballot(p2 != 0);
        unsigned long long b3 = __ballot(p3 != 0);
        if (lane == 0) {
            bm[((c + 0) << 3) + wid] = b0;
            bm[((c + 1) << 3) + wid] = b1;
            bm[((c + 2) << 3) + wid] = b2;
            bm[((c + 3) << 3) + wid] = b3;
        }
    }
    for (; c < nch; c++) {
        int i = (c << 9) + tid;
        float4 q = recq[i < Vc ? i : Vc];
        int p = (i < V) && (sqrtf(sq2_rn(q.x - bx, q.y - by)) <= rad + q.z + SLACK_F);
        unsigned long long bal = __ballot(p != 0);
        if (lane == 0) bm[(c << 3) + wid] = bal;
    }
    __syncthreads();

    // 2) exclusive prefix over ballot words (word order == point-index order)
    if (wid == 0) {
        int run = 0;
        for (int w0 = 0; w0 < NW; w0 += 64) {
            int w = w0 + lane;
            int val = (w < NW) ? __popcll(bm[w]) : 0;
            int incl = wave_incl_scan(val, lane);
            if (w < NW) pfx[w] = run + incl - val;
            run += __shfl(incl, 63, 64);
        }
        if (lane == 0) s_total = run;
    }
    __syncthreads();
    int T = s_total;
    int count = 0;

    // 3) batches of candidates: ordered rank-scatter, then exact-test rounds
    for (int b0 = 0; b0 < T && count < S; b0 += CAP) {
        for (int cc = 0; cc < nch; cc++) {
            unsigned long long bal = bm[(cc << 3) + wid];
            if ((bal >> lane) & 1ull) {
                int w = (cc << 3) + wid;
                int rank = pfx[w] + __popcll(bal & ltmask);
                int rr = rank - b0;
                if (rr >= 0 && rr < CAP) {
                    int i = (cc << 9) + tid;
                    clist[rr] = __float_as_int(recq[i].w);   // vid | np<<16
                }
            }
        }
        __syncthreads();
        int bt = T - b0; if (bt > CAP) bt = CAP;

        // 512 threads = 32 candidates x 16 points per round
        for (int g0 = 0; g0 < bt && count < S; g0 += 32) {
            int ci = g0 + (tid >> 4), k = tid & 15;
            int pred2 = 0;
            size_t n = 0;
            if (ci < bt) {
                int vn = clist[ci];
                int npv = vn >> 16, vid = vn & 0xFFFF;
                if (k < npv) {
                    n = (size_t)vid * K + k;
                    float px = voxels[n * F + 0], py = voxels[n * F + 1];
                    pred2 = (sqrtf(sq2_rn(px - bx, py - by)) <= rad) ? 1 : 0;
                }
            }
            unsigned long long bal2 = __ballot(pred2 != 0);
            if (lane == 0) wsum[wid] = __popcll(bal2);
            __syncthreads();
            int wb = count;
            for (int w2 = 0; w2 < wid; w2++) wb += wsum[w2];
            int tot2 = 0;
            #pragma unroll
            for (int w2 = 0; w2 < WAVES; w2++) tot2 += wsum[w2];
            int pos = wb + __popcll(bal2 & ltmask);
            if (pred2 && pos < S) {
                const float* src = voxels + n * F;
                float* dst = out_kp + ((size_t)r * S + pos) * F;
                #pragma unroll
                for (int j = 0; j < 5; j++) dst[j] = src[j];
            }
            count += tot2;
            __syncthreads();
        }
        __syncthreads();   // clist safe to reuse next batch
    }

    // 4) mask + zero tail
    int sc = count < S ? count : S;
    for (int s = tid; s < S; s += 512)
        out_mask[(size_t)r * S + s] = (s < sc) ? 1.0f : 0.0f;
    for (int j = tid; j < S * F; j += 512) {
        int s = j / F;
        if (s >= sc) out_kp[(size_t)r * S * F + j] = 0.0f;
    }
}

extern "C" void kernel_launch(void* const* d_in, const int* in_sizes, int n_in,
                              void* d_out, int out_size, void* d_ws, size_t ws_size,
                              hipStream_t stream) {
    const float* voxels   = (const float*)d_in[0];
    const float* boxes    = (const float*)d_in[1];
    const float* pc_start = (const float*)d_in[2];
    const int*   coords   = (const int*)d_in[3];
    const int*   num_pts  = (const int*)d_in[4];

    int V = in_sizes[4];                     // 20000
    int R = in_sizes[1] / 7;                 // 256
    int K = 16;
    int F = (in_sizes[0] / V) / K;           // 5
    int S = (out_size - V) / (R * (F + 1));  // 128

    float* out_kp  = (float*)d_out;                 // [R,S,F]
    float* out_msk = out_kp + (size_t)R * S * F;    // [R,S]
    float* out_vox = out_msk + (size_t)R * S;       // [V]

    float4* recq = (float4*)d_ws;                   // V * 16 B

    int nb1 = (V + 255) / 256;                      // 79
    k1_mask<<<nb1, 256, 0, stream>>>(boxes, pc_start, coords, num_pts, voxels,
                                     V, R, K, F, recq, out_vox);
    k2_roi<<<R, 512, 0, stream>>>(voxels, boxes, recq, V, K, F, S,
                                  out_kp, out_msk);
}